// Round 15
// baseline (352.383 us; speedup 1.0000x reference)
//
#include <hip/hip_runtime.h>
#include <hip/hip_bf16.h>
#include <stdint.h>

// B=2, S=2048, D=1024, H=16, dh=64. All matrices row-major.
// ws (bf16 elems): qc kc vc (4M each) | wtq wtk wtv wto (1M each) |
//   qb kb vb ctx (4M each) = 64 MB. Aliases after proj: vbT(4M)=qc;
//   ctx32 (4M f32 = 16MB) = kc+vc; l32 (32*2048 f32) = wtq.
// qb/kb stored with within-head d-permutation sigma (QK^T invariant).
// vbT uses within-32-group key permutation tau matching P-fragment order.
// == Round 14 (verified, 120.8us) + split-K=2 attention with exact f32
//    atomic combine (no-max softmax -> partials are pure sums). ==

typedef __attribute__((ext_vector_type(8))) short bf16x8;
typedef __attribute__((ext_vector_type(4))) float f32x4;

#define LOG2E 1.44269504088896340736f

union F8 {
    uint64_t u64[2];
    unsigned u32[4];
    unsigned short s[8];
    bf16x8 v;
    uint4 q;
};

__device__ __forceinline__ unsigned short f2b(float f) {
    union { float f; unsigned u; } x; x.f = f;
    unsigned r = x.u + 0x7FFF + ((x.u >> 16) & 1);  // RNE
    return (unsigned short)(r >> 16);
}

// Hardware exp2 (verified round 10: bit-identical output, -22% VALUBusy).
#if __has_builtin(__builtin_amdgcn_exp2f)
__device__ __forceinline__ float fexp2(float x) { return __builtin_amdgcn_exp2f(x); }
#else
extern "C" __device__ float __ocml_native_exp2_f32(float);
__device__ __forceinline__ float fexp2(float x) { return __ocml_native_exp2_f32(x); }
#endif

__device__ __forceinline__ void gload_lds16(const void* g, void* l) {
    __builtin_amdgcn_global_load_lds(
        (const __attribute__((address_space(1))) void*)g,
        (__attribute__((address_space(3))) void*)l, 16, 0, 0);
}

#define MFMA16(A, B, C) __builtin_amdgcn_mfma_f32_16x16x32_bf16(A, B, C, 0, 0, 0)

// ---------------------------------------------------------------------------
// Fused prep: z<3 -> fp32->bf16 convert of Q/K/V (4096 blocks each);
// z==3 -> Wt[n][k]=bf16(W[k][n]) for 4 weights (1024 blocks, rest exit).
// ---------------------------------------------------------------------------
__global__ __launch_bounds__(256) void prep_kernel(
    const float* __restrict__ Q, const float* __restrict__ K, const float* __restrict__ V,
    const float* __restrict__ Wq, const float* __restrict__ Wk,
    const float* __restrict__ Wv, const float* __restrict__ Wo,
    unsigned short* __restrict__ qc, unsigned short* __restrict__ kc,
    unsigned short* __restrict__ vc,
    unsigned short* __restrict__ wtq, unsigned short* __restrict__ wtk,
    unsigned short* __restrict__ wtv, unsigned short* __restrict__ wto)
{
    __shared__ unsigned short T[64][68];
    const int z = blockIdx.z;
    if (z < 3) {
        const float* src = (z == 0) ? Q : ((z == 1) ? K : V);
        unsigned short* dst = (z == 0) ? qc : ((z == 1) ? kc : vc);
        const size_t i = ((size_t)blockIdx.x * 256 + threadIdx.x) * 4;
        const float4 v = *(const float4*)(src + i);
        ushort4 o;
        o.x = f2b(v.x); o.y = f2b(v.y); o.z = f2b(v.z); o.w = f2b(v.w);
        *(ushort4*)(dst + i) = o;
        return;
    }
    if (blockIdx.x >= 1024) return;   // uniform early exit (whole block)
    const int w  = blockIdx.x >> 8;          // weight id 0..3
    const int kt = blockIdx.x & 15;          // k-tile
    const int nt = (blockIdx.x >> 4) & 15;   // n-tile
    const float* W = (w == 0) ? Wq : ((w == 1) ? Wk : ((w == 2) ? Wv : Wo));
    unsigned short* Wt = (w == 0) ? wtq : ((w == 1) ? wtk : ((w == 2) ? wtv : wto));

    const int t = threadIdx.x;
    const int r = t >> 2, cg = t & 3;
    const int k0 = kt * 64, n0 = nt * 64;

#pragma unroll
    for (int i = 0; i < 4; i++) {
        const float4 v = *(const float4*)(W + (size_t)(k0 + r) * 1024 + n0 + cg * 16 + i * 4);
        T[r][cg * 16 + i * 4 + 0] = f2b(v.x);
        T[r][cg * 16 + i * 4 + 1] = f2b(v.y);
        T[r][cg * 16 + i * 4 + 2] = f2b(v.z);
        T[r][cg * 16 + i * 4 + 3] = f2b(v.w);
    }
    __syncthreads();
#pragma unroll
    for (int i = 0; i < 4; i++) {
        ushort4 o;
        o.x = T[cg * 16 + i * 4 + 0][r];
        o.y = T[cg * 16 + i * 4 + 1][r];
        o.z = T[cg * 16 + i * 4 + 2][r];
        o.w = T[cg * 16 + i * 4 + 3][r];
        *(ushort4*)(Wt + (size_t)(n0 + r) * 1024 + k0 + cg * 16 + i * 4) = o;
    }
}

// ---------------------------------------------------------------------------
// Prep: vbT[bh*64+d][stored key] with tau: key (16a+4g+r) -> pos (8g+4a+r).
// ---------------------------------------------------------------------------
__global__ __launch_bounds__(256) void transpose_v_kernel(
    const unsigned short* __restrict__ vb, unsigned short* __restrict__ vbT)
{
    __shared__ unsigned short T[64][68];
    const int kt = blockIdx.x;
    const int bh = blockIdx.y;
    const int b = bh >> 4, h = bh & 15;
    const int k0 = kt * 64;
    const int r = threadIdx.x >> 3, c8 = threadIdx.x & 7;

    const unsigned short* src = vb + ((size_t)b * 2048 + k0 + r) * 1024 + h * 64 + c8 * 8;
    F8 v0, v1;
    v0.q = *(const uint4*)src;
    v1.q = *(const uint4*)(src + 32 * 1024);
    *(uint64_t*)&T[r][c8 * 8]           = v0.u64[0];
    *(uint64_t*)&T[r][c8 * 8 + 4]       = v0.u64[1];
    *(uint64_t*)&T[r + 32][c8 * 8]      = v1.u64[0];
    *(uint64_t*)&T[r + 32][c8 * 8 + 4]  = v1.u64[1];
    __syncthreads();

    const int dd = threadIdx.x >> 3, k8 = threadIdx.x & 7;
    F8 o0, o1;
#pragma unroll
    for (int i = 0; i < 8; i++) {
        o0.s[i] = T[k8 * 8 + i][dd];
        o1.s[i] = T[k8 * 8 + i][dd + 32];
    }
    const int kk = k0 + k8 * 8;
    const int base32 = kk & ~31;
    const int qd0 = (kk >> 2) & 7, qd1 = qd0 + 1;
    const int sq0 = 2 * (qd0 & 3) + (qd0 >> 2);
    const int sq1 = 2 * (qd1 & 3) + (qd1 >> 2);
    unsigned short* row0 = vbT + ((size_t)bh * 64 + dd) * 2048;
    *(uint64_t*)(row0 + base32 + sq0 * 4) = o0.u64[0];
    *(uint64_t*)(row0 + base32 + sq1 * 4) = o0.u64[1];
    *(uint64_t*)(row0 + 32 * 2048 + base32 + sq0 * 4) = o1.u64[0];
    *(uint64_t*)(row0 + 32 * 2048 + base32 + sq1 * 4) = o1.u64[1];
}

// ---------------------------------------------------------------------------
// m97-style bf16 GEMM. perm (runtime, block-uniform, epilogue-only).
// ---------------------------------------------------------------------------
template<bool OUT_F32>
__device__ __forceinline__ void gemm_bf16_body(
    const unsigned short* __restrict__ A, const unsigned short* __restrict__ Bt,
    const float* __restrict__ bias, void* __restrict__ outv, const bool perm)
{
    __shared__ unsigned short As[2][128][32];
    __shared__ unsigned short Bs[2][128][32];

    const int tid  = threadIdx.x;
    const int lane = tid & 63;
    const int wid  = tid >> 6;
    const int g    = lane >> 4;
    const int lq   = lane & 15;
    const int wm   = wid >> 1;
    const int wn   = wid & 1;
    const int Mbase = blockIdx.x * 128;
    const int Nbase = blockIdx.y * 128;

    const int srow = lane >> 2;
    const int scol = (lane & 3) * 8;

#define STAGE(BF, KT) do { \
        _Pragma("unroll") \
        for (int c = 0; c < 2; c++) { \
            const int ch = wid * 2 + c; \
            gload_lds16(A  + (size_t)(Mbase + ch * 16 + srow) * 1024 + (KT) + scol, \
                        &As[BF][ch * 16][0]); \
            gload_lds16(Bt + (size_t)(Nbase + ch * 16 + srow) * 1024 + (KT) + scol, \
                        &Bs[BF][ch * 16][0]); \
        } \
    } while (0)

    f32x4 acc[4][4];
#pragma unroll
    for (int i = 0; i < 4; i++)
#pragma unroll
        for (int j = 0; j < 4; j++)
            acc[i][j] = (f32x4){0.f, 0.f, 0.f, 0.f};

    STAGE(0, 0);
    __syncthreads();

    int cur = 0;
    for (int kt = 0; kt < 1024; kt += 32) {
        if (kt < 992) STAGE(cur ^ 1, kt + 32);

        F8 af[4], bfr[4];
#pragma unroll
        for (int mi = 0; mi < 4; mi++)
            af[mi].v = *(const bf16x8*)&As[cur][wm * 64 + mi * 16 + lq][8 * g];
#pragma unroll
        for (int ni = 0; ni < 4; ni++)
            bfr[ni].v = *(const bf16x8*)&Bs[cur][wn * 64 + ni * 16 + lq][8 * g];

        __builtin_amdgcn_s_setprio(1);
#pragma unroll
        for (int mi = 0; mi < 4; mi++)
#pragma unroll
            for (int ni = 0; ni < 4; ni++)
                acc[mi][ni] = MFMA16(af[mi].v, bfr[ni].v, acc[mi][ni]);
        __builtin_amdgcn_s_setprio(0);

        __syncthreads();
        cur ^= 1;
    }

#pragma unroll
    for (int mi = 0; mi < 4; mi++) {
#pragma unroll
        for (int ni = 0; ni < 4; ni++) {
            const int d_nat = ni * 16 + lq;            // 0..63 within head
            const float bb = bias[Nbase + wn * 64 + d_nat];
            const int d_prm = (ni >> 1) * 32 + (lq >> 2) * 8 + (ni & 1) * 4 + (lq & 3);
            const int ng = Nbase + wn * 64 + (perm ? d_prm : d_nat);
#pragma unroll
            for (int r = 0; r < 4; r++) {
                int mg = Mbase + wm * 64 + mi * 16 + g * 4 + r;
                float val = acc[mi][ni][r] + bb;
                if (OUT_F32)
                    ((float*)outv)[(size_t)mg * 1024 + ng] = val;
                else
                    ((unsigned short*)outv)[(size_t)mg * 1024 + ng] = f2b(val);
            }
        }
    }
#undef STAGE
}

__global__ __launch_bounds__(256) void proj_kernel(
    const unsigned short* __restrict__ qc, const unsigned short* __restrict__ kc,
    const unsigned short* __restrict__ vc,
    const unsigned short* __restrict__ wtq, const unsigned short* __restrict__ wtk,
    const unsigned short* __restrict__ wtv,
    const float* __restrict__ bq, const float* __restrict__ bk,
    const float* __restrict__ bv,
    unsigned short* qb, unsigned short* kb, unsigned short* vb)
{
    const int z = blockIdx.z;
    const unsigned short* A  = (z == 0) ? qc : ((z == 1) ? kc : vc);
    const unsigned short* Bt = (z == 0) ? wtq : ((z == 1) ? wtk : wtv);
    const float* bias = (z == 0) ? bq : ((z == 1) ? bk : bv);
    unsigned short* out = (z == 0) ? qb : ((z == 1) ? kb : vb);
    gemm_bf16_body<false>(A, Bt, bias, out, z != 2);
}

__global__ __launch_bounds__(256) void out_proj_kernel(
    const unsigned short* __restrict__ ctx, const unsigned short* __restrict__ wto,
    const float* __restrict__ bo, float* __restrict__ out)
{
    gemm_bf16_body<true>(ctx, wto, bo, out, false);
}

// ---------------------------------------------------------------------------
// Flash attention v13: split-K=2. Each block handles 16 KV windows (half the
// keys) for 128 queries of one (b,h); per-wave program = round-11 verified
// 2-buffer pipeline. Partials are EXACT sums (no-max softmax): f32 atomicAdd
// into ctx32/l32 (2 contributions per location: fp-add commutative + 0+x
// exact -> deterministic). Grid 1024 = 4 blocks/CU = 16 waves/CU.
// ---------------------------------------------------------------------------
__global__ __launch_bounds__(256, 4) void attn_kernel(
    const unsigned short* __restrict__ qb,
    const unsigned short* __restrict__ kb,
    const unsigned short* __restrict__ vbT,
    float* __restrict__ ctx32,
    float* __restrict__ l32)
{
    __shared__ unsigned short Ks[2][64][72];  // [buf][key][stored d]
    __shared__ unsigned short Vt[2][64][72];  // [buf][d][stored key]

    const int tid  = threadIdx.x;
    const int lane = tid & 63;
    const int wave = tid >> 6;
    const int g    = lane >> 4;
    const int lq   = lane & 15;
    // XCD swizzle (bijective on 1024): wg = split*512 + qt*32 + (bh&3)*8 + (bh>>2)
    const int wg    = blockIdx.x + 16 * blockIdx.y + 512 * blockIdx.z;  // 0..1023
    const int bh    = (wg & 7) * 4 + ((wg >> 3) & 3);                   // 0..31
    const int rest  = wg >> 5;                                          // 0..31
    const int qt    = rest & 15;                                        // 0..15
    const int split = rest >> 4;                                        // 0..1
    const int b = bh >> 4, h = bh & 15;
    const int qw = qt * 128 + wave * 32;

    const size_t kvoff = ((size_t)b * 2048) * 1024 + (size_t)h * 64
                       + (size_t)split * 1024 * 1024;   // key offset 1024 rows

    // Q fragments: stored cols [32hf + 8g .. +7], single uint4 each; 2 q-frags
    F8 qf[2][2];
#pragma unroll
    for (int qi = 0; qi < 2; qi++) {
        const size_t qoff = ((size_t)(b * 2048 + qw + qi * 16 + lq)) * 1024 + h * 64;
        qf[qi][0].q = *(const uint4*)(qb + qoff + 8 * g);
        qf[qi][1].q = *(const uint4*)(qb + qoff + 32 + 8 * g);
    }

    const int sr = tid >> 3, sc8 = tid & 7;
    const unsigned short* kbase  = kb + kvoff + (size_t)sr * 1024 + sc8 * 8;
    const unsigned short* vtbase = vbT + ((size_t)bh * 64 + sr) * 2048
                                 + split * 1024 + sc8 * 8;

    uint4 kx0, kx1, vx0, vx1;
#define LOADW(KW) do { \
        const unsigned short* kp = kbase + (size_t)(KW) * 1024; \
        const unsigned short* vp = vtbase + (KW); \
        kx0 = *(const uint4*)kp;  kx1 = *(const uint4*)(kp + 32 * 1024); \
        vx0 = *(const uint4*)vp;  vx1 = *(const uint4*)(vp + 32 * 2048); \
    } while (0)
#define WRITEW(BUF) do { \
        *(uint4*)&Ks[BUF][sr][sc8 * 8]      = kx0; \
        *(uint4*)&Ks[BUF][sr + 32][sc8 * 8] = kx1; \
        *(uint4*)&Vt[BUF][sr][sc8 * 8]      = vx0; \
        *(uint4*)&Vt[BUF][sr + 32][sc8 * 8] = vx1; \
    } while (0)

    float lrun0 = 0.f, lrun1 = 0.f;
    f32x4 acc[4][2];
#pragma unroll
    for (int db = 0; db < 4; db++) {
        acc[db][0] = (f32x4){0.f, 0.f, 0.f, 0.f};
        acc[db][1] = (f32x4){0.f, 0.f, 0.f, 0.f};
    }

    const float SE = 0.03125f * LOG2E;

#define QKSM(CURN, PF) do { \
        _Pragma("unroll") \
        for (int kbi = 0; kbi < 4; kbi++) { \
            const unsigned short* kr = &Ks[CURN][kbi * 16 + lq][0]; \
            F8 kf0, kf1; \
            kf0.q = *(const uint4*)(kr + 8 * g); \
            kf1.q = *(const uint4*)(kr + 32 + 8 * g); \
            f32x4 st0 = (f32x4){0.f, 0.f, 0.f, 0.f}; \
            f32x4 st1 = (f32x4){0.f, 0.f, 0.f, 0.f}; \
            st0 = MFMA16(kf0.v, qf[0][0].v, st0); \
            st0 = MFMA16(kf1.v, qf[0][1].v, st0); \
            st1 = MFMA16(kf0.v, qf[1][0].v, st1); \
            st1 = MFMA16(kf1.v, qf[1][1].v, st1); \
            float a0 = fexp2(st0[0] * SE), a1 = fexp2(st0[1] * SE); \
            float a2 = fexp2(st0[2] * SE), a3 = fexp2(st0[3] * SE); \
            float b0 = fexp2(st1[0] * SE), b1 = fexp2(st1[1] * SE); \
            float b2 = fexp2(st1[2] * SE), b3 = fexp2(st1[3] * SE); \
            lrun0 += (a0 + a1) + (a2 + a3); \
            lrun1 += (b0 + b1) + (b2 + b3); \
            unsigned wa0, wa1, wb0, wb1; \
            asm("v_cvt_pk_bf16_f32 %0, %1, %2" : "=v"(wa0) : "v"(a0), "v"(a1)); \
            asm("v_cvt_pk_bf16_f32 %0, %1, %2" : "=v"(wa1) : "v"(a2), "v"(a3)); \
            asm("v_cvt_pk_bf16_f32 %0, %1, %2" : "=v"(wb0) : "v"(b0), "v"(b1)); \
            asm("v_cvt_pk_bf16_f32 %0, %1, %2" : "=v"(wb1) : "v"(b2), "v"(b3)); \
            PF[0][kbi >> 1].u32[(kbi & 1) * 2 + 0] = wa0; \
            PF[0][kbi >> 1].u32[(kbi & 1) * 2 + 1] = wa1; \
            PF[1][kbi >> 1].u32[(kbi & 1) * 2 + 0] = wb0; \
            PF[1][kbi >> 1].u32[(kbi & 1) * 2 + 1] = wb1; \
        } \
    } while (0)

#define PVSTEP(CURN, PF) do { \
        _Pragma("unroll") \
        for (int kg = 0; kg < 2; kg++) { \
            F8 vf0, vf1, vf2, vf3; \
            vf0.q = *(const uint4*)(&Vt[CURN][ 0 + lq][kg * 32] + 8 * g); \
            vf1.q = *(const uint4*)(&Vt[CURN][16 + lq][kg * 32] + 8 * g); \
            vf2.q = *(const uint4*)(&Vt[CURN][32 + lq][kg * 32] + 8 * g); \
            vf3.q = *(const uint4*)(&Vt[CURN][48 + lq][kg * 32] + 8 * g); \
            __builtin_amdgcn_s_setprio(1); \
            acc[0][0] = MFMA16(vf0.v, PF[0][kg].v, acc[0][0]); \
            acc[1][0] = MFMA16(vf1.v, PF[0][kg].v, acc[1][0]); \
            acc[2][0] = MFMA16(vf2.v, PF[0][kg].v, acc[2][0]); \
            acc[3][0] = MFMA16(vf3.v, PF[0][kg].v, acc[3][0]); \
            acc[0][1] = MFMA16(vf0.v, PF[1][kg].v, acc[0][1]); \
            acc[1][1] = MFMA16(vf1.v, PF[1][kg].v, acc[1][1]); \
            acc[2][1] = MFMA16(vf2.v, PF[1][kg].v, acc[2][1]); \
            acc[3][1] = MFMA16(vf3.v, PF[1][kg].v, acc[3][1]); \
            __builtin_amdgcn_s_setprio(0); \
        } \
    } while (0)

    F8 pfA[2][2], pfB[2][2];

    // prologue: stage w0, compute P(0); stage w1  (16 windows this split)
    LOADW(0);
    WRITEW(0);
    __syncthreads();
    QKSM(0, pfA);
    LOADW(64);
    WRITEW(1);
    __syncthreads();

#define WBODY(CUR, T, PF_CUR, PF_NXT) do { \
        if ((T) + 2 < 16) LOADW(((T) + 2) * 64); \
        if ((T) + 1 < 16) QKSM((CUR) ^ 1, PF_NXT); \
        PVSTEP(CUR, PF_CUR); \
        __syncthreads(); \
        if ((T) + 2 < 16) WRITEW(CUR); \
        __syncthreads(); \
    } while (0)

    for (int t = 0; t < 16; t += 2) {
        WBODY(0, t,     pfA, pfB);
        WBODY(1, t + 1, pfB, pfA);
    }

    // epilogue: reduce l across g-groups; atomically accumulate partials.
    lrun0 += __shfl_xor(lrun0, 16);
    lrun0 += __shfl_xor(lrun0, 32);
    lrun1 += __shfl_xor(lrun1, 16);
    lrun1 += __shfl_xor(lrun1, 32);
    if (lane < 16) {
        atomicAdd(&l32[(size_t)bh * 2048 + qw + lane], lrun0);
        atomicAdd(&l32[(size_t)bh * 2048 + qw + 16 + lane], lrun1);
    }
#pragma unroll
    for (int qi = 0; qi < 2; qi++) {
        const size_t crow = ((size_t)(b * 2048 + qw + qi * 16 + lq)) * 1024 + h * 64;
#pragma unroll
        for (int db = 0; db < 4; db++)
#pragma unroll
            for (int r = 0; r < 4; r++)
                atomicAdd(&ctx32[crow + db * 16 + g * 4 + r], acc[db][qi][r]);
    }
#undef LOADW
#undef WRITEW
#undef QKSM
#undef PVSTEP
#undef WBODY
}

// ---------------------------------------------------------------------------
// Combine: ctx[token][col] = bf16( ctx32[token][col] / l32[bh][q] ).
// grid 4096 x 256 threads (4 cols each).
// ---------------------------------------------------------------------------
__global__ __launch_bounds__(256) void combine_kernel(
    const float* __restrict__ ctx32, const float* __restrict__ l32,
    unsigned short* __restrict__ ctx)
{
    const int token = blockIdx.x;               // 0..4095
    const int col   = threadIdx.x * 4;          // 0..1020
    const int h     = col >> 6;
    const int bh    = (token >> 11) * 16 + h;
    const float l   = l32[(size_t)bh * 2048 + (token & 2047)];
    const float inv = 1.f / l;
    const float4 a  = *(const float4*)(ctx32 + (size_t)token * 1024 + col);
    ushort4 o;
    o.x = f2b(a.x * inv); o.y = f2b(a.y * inv);
    o.z = f2b(a.z * inv); o.w = f2b(a.w * inv);
    *(ushort4*)(ctx + (size_t)token * 1024 + col) = o;
}

// ---------------------------------------------------------------------------
extern "C" void kernel_launch(void* const* d_in, const int* in_sizes, int n_in,
                              void* d_out, int out_size, void* d_ws, size_t ws_size,
                              hipStream_t stream) {
    const float* V  = (const float*)d_in[0];
    const float* Q  = (const float*)d_in[1];
    const float* K  = (const float*)d_in[2];
    const float* Wq = (const float*)d_in[3];
    const float* bq = (const float*)d_in[4];
    const float* Wk = (const float*)d_in[5];
    const float* bk = (const float*)d_in[6];
    const float* Wv = (const float*)d_in[7];
    const float* bv = (const float*)d_in[8];
    const float* Wo = (const float*)d_in[9];
    const float* bo = (const float*)d_in[10];

    const size_t M4 = (size_t)4096 * 1024;
    const size_t M1 = (size_t)1024 * 1024;
    unsigned short* qc  = (unsigned short*)d_ws;
    unsigned short* kc  = qc + M4;
    unsigned short* vc  = kc + M4;
    unsigned short* wtq = vc + M4;
    unsigned short* wtk = wtq + M1;
    unsigned short* wtv = wtk + M1;
    unsigned short* wto = wtv + M1;
    unsigned short* qb  = wto + M1;
    unsigned short* kb  = qb + M4;
    unsigned short* vb  = kb + M4;
    unsigned short* ctx = vb + M4;
    unsigned short* vbT = qc;            // alias: qc dead after proj_kernel
    float* ctx32 = (float*)kc;           // alias: kc+vc (16MB) dead after proj
    float* l32   = (float*)wtq;          // alias: wtq (2MB) dead after proj

    prep_kernel<<<dim3(4096, 1, 4), 256, 0, stream>>>(
        Q, K, V, Wq, Wk, Wv, Wo, qc, kc, vc, wtq, wtk, wtv, wto);
    proj_kernel<<<dim3(32, 8, 3), 256, 0, stream>>>(
        qc, kc, vc, wtq, wtk, wtv, bq, bk, bv, qb, kb, vb);
    transpose_v_kernel<<<dim3(32, 32), 256, 0, stream>>>(vb, vbT);
    hipMemsetAsync(ctx32, 0, M4 * sizeof(float), stream);
    hipMemsetAsync(l32, 0, (size_t)32 * 2048 * sizeof(float), stream);
    attn_kernel<<<dim3(16, 32, 2), 256, 0, stream>>>(qb, kb, vbT, ctx32, l32);
    combine_kernel<<<dim3(4096), 256, 0, stream>>>(ctx32, l32, ctx);
    out_proj_kernel<<<dim3(32, 8), 256, 0, stream>>>(ctx, wto, bo, (float*)d_out);
}

// Round 16
// 218.470 us; speedup vs baseline: 1.6130x; 1.6130x over previous
//
#include <hip/hip_runtime.h>
#include <hip/hip_bf16.h>
#include <stdint.h>

// B=2, S=2048, D=1024, H=16, dh=64. All matrices row-major.
// ws (bf16 elems): qc kc vc (4M each) | wtq wtk wtv wto (1M each) |
//   qb kb vb ctx (4M each) = 64 MB. Aliases after proj: vbT(4M)=qc;
//   ctx32 (4M f32 = 16MB) = kc+vc; l32 (32*2048 f32) = wtq.
// qb/kb stored with within-head d-permutation sigma (QK^T invariant).
// vbT uses within-32-group key permutation tau matching P-fragment order.
// == Round 15 machinery (split-K=2, exact atomic combine — correctness
//    verified) with the ONE change: attn __launch_bounds__(256,2) (the
//    (256,4) hint made the compiler clamp to 64 VGPR and spill ~600MB). ==

typedef __attribute__((ext_vector_type(8))) short bf16x8;
typedef __attribute__((ext_vector_type(4))) float f32x4;

#define LOG2E 1.44269504088896340736f

union F8 {
    uint64_t u64[2];
    unsigned u32[4];
    unsigned short s[8];
    bf16x8 v;
    uint4 q;
};

__device__ __forceinline__ unsigned short f2b(float f) {
    union { float f; unsigned u; } x; x.f = f;
    unsigned r = x.u + 0x7FFF + ((x.u >> 16) & 1);  // RNE
    return (unsigned short)(r >> 16);
}

// Hardware exp2 (verified round 10: bit-identical output, -22% VALUBusy).
#if __has_builtin(__builtin_amdgcn_exp2f)
__device__ __forceinline__ float fexp2(float x) { return __builtin_amdgcn_exp2f(x); }
#else
extern "C" __device__ float __ocml_native_exp2_f32(float);
__device__ __forceinline__ float fexp2(float x) { return __ocml_native_exp2_f32(x); }
#endif

__device__ __forceinline__ void gload_lds16(const void* g, void* l) {
    __builtin_amdgcn_global_load_lds(
        (const __attribute__((address_space(1))) void*)g,
        (__attribute__((address_space(3))) void*)l, 16, 0, 0);
}

#define MFMA16(A, B, C) __builtin_amdgcn_mfma_f32_16x16x32_bf16(A, B, C, 0, 0, 0)

// ---------------------------------------------------------------------------
// Fused prep: z<3 -> fp32->bf16 convert of Q/K/V (4096 blocks each);
// z==3 -> Wt[n][k]=bf16(W[k][n]) for 4 weights (1024 blocks, rest exit).
// ---------------------------------------------------------------------------
__global__ __launch_bounds__(256) void prep_kernel(
    const float* __restrict__ Q, const float* __restrict__ K, const float* __restrict__ V,
    const float* __restrict__ Wq, const float* __restrict__ Wk,
    const float* __restrict__ Wv, const float* __restrict__ Wo,
    unsigned short* __restrict__ qc, unsigned short* __restrict__ kc,
    unsigned short* __restrict__ vc,
    unsigned short* __restrict__ wtq, unsigned short* __restrict__ wtk,
    unsigned short* __restrict__ wtv, unsigned short* __restrict__ wto)
{
    __shared__ unsigned short T[64][68];
    const int z = blockIdx.z;
    if (z < 3) {
        const float* src = (z == 0) ? Q : ((z == 1) ? K : V);
        unsigned short* dst = (z == 0) ? qc : ((z == 1) ? kc : vc);
        const size_t i = ((size_t)blockIdx.x * 256 + threadIdx.x) * 4;
        const float4 v = *(const float4*)(src + i);
        ushort4 o;
        o.x = f2b(v.x); o.y = f2b(v.y); o.z = f2b(v.z); o.w = f2b(v.w);
        *(ushort4*)(dst + i) = o;
        return;
    }
    if (blockIdx.x >= 1024) return;   // uniform early exit (whole block)
    const int w  = blockIdx.x >> 8;          // weight id 0..3
    const int kt = blockIdx.x & 15;          // k-tile
    const int nt = (blockIdx.x >> 4) & 15;   // n-tile
    const float* W = (w == 0) ? Wq : ((w == 1) ? Wk : ((w == 2) ? Wv : Wo));
    unsigned short* Wt = (w == 0) ? wtq : ((w == 1) ? wtk : ((w == 2) ? wtv : wto));

    const int t = threadIdx.x;
    const int r = t >> 2, cg = t & 3;
    const int k0 = kt * 64, n0 = nt * 64;

#pragma unroll
    for (int i = 0; i < 4; i++) {
        const float4 v = *(const float4*)(W + (size_t)(k0 + r) * 1024 + n0 + cg * 16 + i * 4);
        T[r][cg * 16 + i * 4 + 0] = f2b(v.x);
        T[r][cg * 16 + i * 4 + 1] = f2b(v.y);
        T[r][cg * 16 + i * 4 + 2] = f2b(v.z);
        T[r][cg * 16 + i * 4 + 3] = f2b(v.w);
    }
    __syncthreads();
#pragma unroll
    for (int i = 0; i < 4; i++) {
        ushort4 o;
        o.x = T[cg * 16 + i * 4 + 0][r];
        o.y = T[cg * 16 + i * 4 + 1][r];
        o.z = T[cg * 16 + i * 4 + 2][r];
        o.w = T[cg * 16 + i * 4 + 3][r];
        *(ushort4*)(Wt + (size_t)(n0 + r) * 1024 + k0 + cg * 16 + i * 4) = o;
    }
}

// ---------------------------------------------------------------------------
// Prep: vbT[bh*64+d][stored key] with tau: key (16a+4g+r) -> pos (8g+4a+r).
// ---------------------------------------------------------------------------
__global__ __launch_bounds__(256) void transpose_v_kernel(
    const unsigned short* __restrict__ vb, unsigned short* __restrict__ vbT)
{
    __shared__ unsigned short T[64][68];
    const int kt = blockIdx.x;
    const int bh = blockIdx.y;
    const int b = bh >> 4, h = bh & 15;
    const int k0 = kt * 64;
    const int r = threadIdx.x >> 3, c8 = threadIdx.x & 7;

    const unsigned short* src = vb + ((size_t)b * 2048 + k0 + r) * 1024 + h * 64 + c8 * 8;
    F8 v0, v1;
    v0.q = *(const uint4*)src;
    v1.q = *(const uint4*)(src + 32 * 1024);
    *(uint64_t*)&T[r][c8 * 8]           = v0.u64[0];
    *(uint64_t*)&T[r][c8 * 8 + 4]       = v0.u64[1];
    *(uint64_t*)&T[r + 32][c8 * 8]      = v1.u64[0];
    *(uint64_t*)&T[r + 32][c8 * 8 + 4]  = v1.u64[1];
    __syncthreads();

    const int dd = threadIdx.x >> 3, k8 = threadIdx.x & 7;
    F8 o0, o1;
#pragma unroll
    for (int i = 0; i < 8; i++) {
        o0.s[i] = T[k8 * 8 + i][dd];
        o1.s[i] = T[k8 * 8 + i][dd + 32];
    }
    const int kk = k0 + k8 * 8;
    const int base32 = kk & ~31;
    const int qd0 = (kk >> 2) & 7, qd1 = qd0 + 1;
    const int sq0 = 2 * (qd0 & 3) + (qd0 >> 2);
    const int sq1 = 2 * (qd1 & 3) + (qd1 >> 2);
    unsigned short* row0 = vbT + ((size_t)bh * 64 + dd) * 2048;
    *(uint64_t*)(row0 + base32 + sq0 * 4) = o0.u64[0];
    *(uint64_t*)(row0 + base32 + sq1 * 4) = o0.u64[1];
    *(uint64_t*)(row0 + 32 * 2048 + base32 + sq0 * 4) = o1.u64[0];
    *(uint64_t*)(row0 + 32 * 2048 + base32 + sq1 * 4) = o1.u64[1];
}

// ---------------------------------------------------------------------------
// m97-style bf16 GEMM. perm (runtime, block-uniform, epilogue-only).
// ---------------------------------------------------------------------------
template<bool OUT_F32>
__device__ __forceinline__ void gemm_bf16_body(
    const unsigned short* __restrict__ A, const unsigned short* __restrict__ Bt,
    const float* __restrict__ bias, void* __restrict__ outv, const bool perm)
{
    __shared__ unsigned short As[2][128][32];
    __shared__ unsigned short Bs[2][128][32];

    const int tid  = threadIdx.x;
    const int lane = tid & 63;
    const int wid  = tid >> 6;
    const int g    = lane >> 4;
    const int lq   = lane & 15;
    const int wm   = wid >> 1;
    const int wn   = wid & 1;
    const int Mbase = blockIdx.x * 128;
    const int Nbase = blockIdx.y * 128;

    const int srow = lane >> 2;
    const int scol = (lane & 3) * 8;

#define STAGE(BF, KT) do { \
        _Pragma("unroll") \
        for (int c = 0; c < 2; c++) { \
            const int ch = wid * 2 + c; \
            gload_lds16(A  + (size_t)(Mbase + ch * 16 + srow) * 1024 + (KT) + scol, \
                        &As[BF][ch * 16][0]); \
            gload_lds16(Bt + (size_t)(Nbase + ch * 16 + srow) * 1024 + (KT) + scol, \
                        &Bs[BF][ch * 16][0]); \
        } \
    } while (0)

    f32x4 acc[4][4];
#pragma unroll
    for (int i = 0; i < 4; i++)
#pragma unroll
        for (int j = 0; j < 4; j++)
            acc[i][j] = (f32x4){0.f, 0.f, 0.f, 0.f};

    STAGE(0, 0);
    __syncthreads();

    int cur = 0;
    for (int kt = 0; kt < 1024; kt += 32) {
        if (kt < 992) STAGE(cur ^ 1, kt + 32);

        F8 af[4], bfr[4];
#pragma unroll
        for (int mi = 0; mi < 4; mi++)
            af[mi].v = *(const bf16x8*)&As[cur][wm * 64 + mi * 16 + lq][8 * g];
#pragma unroll
        for (int ni = 0; ni < 4; ni++)
            bfr[ni].v = *(const bf16x8*)&Bs[cur][wn * 64 + ni * 16 + lq][8 * g];

        __builtin_amdgcn_s_setprio(1);
#pragma unroll
        for (int mi = 0; mi < 4; mi++)
#pragma unroll
            for (int ni = 0; ni < 4; ni++)
                acc[mi][ni] = MFMA16(af[mi].v, bfr[ni].v, acc[mi][ni]);
        __builtin_amdgcn_s_setprio(0);

        __syncthreads();
        cur ^= 1;
    }

#pragma unroll
    for (int mi = 0; mi < 4; mi++) {
#pragma unroll
        for (int ni = 0; ni < 4; ni++) {
            const int d_nat = ni * 16 + lq;            // 0..63 within head
            const float bb = bias[Nbase + wn * 64 + d_nat];
            const int d_prm = (ni >> 1) * 32 + (lq >> 2) * 8 + (ni & 1) * 4 + (lq & 3);
            const int ng = Nbase + wn * 64 + (perm ? d_prm : d_nat);
#pragma unroll
            for (int r = 0; r < 4; r++) {
                int mg = Mbase + wm * 64 + mi * 16 + g * 4 + r;
                float val = acc[mi][ni][r] + bb;
                if (OUT_F32)
                    ((float*)outv)[(size_t)mg * 1024 + ng] = val;
                else
                    ((unsigned short*)outv)[(size_t)mg * 1024 + ng] = f2b(val);
            }
        }
    }
#undef STAGE
}

__global__ __launch_bounds__(256) void proj_kernel(
    const unsigned short* __restrict__ qc, const unsigned short* __restrict__ kc,
    const unsigned short* __restrict__ vc,
    const unsigned short* __restrict__ wtq, const unsigned short* __restrict__ wtk,
    const unsigned short* __restrict__ wtv,
    const float* __restrict__ bq, const float* __restrict__ bk,
    const float* __restrict__ bv,
    unsigned short* qb, unsigned short* kb, unsigned short* vb)
{
    const int z = blockIdx.z;
    const unsigned short* A  = (z == 0) ? qc : ((z == 1) ? kc : vc);
    const unsigned short* Bt = (z == 0) ? wtq : ((z == 1) ? wtk : wtv);
    const float* bias = (z == 0) ? bq : ((z == 1) ? bk : bv);
    unsigned short* out = (z == 0) ? qb : ((z == 1) ? kb : vb);
    gemm_bf16_body<false>(A, Bt, bias, out, z != 2);
}

__global__ __launch_bounds__(256) void out_proj_kernel(
    const unsigned short* __restrict__ ctx, const unsigned short* __restrict__ wto,
    const float* __restrict__ bo, float* __restrict__ out)
{
    gemm_bf16_body<true>(ctx, wto, bo, out, false);
}

// ---------------------------------------------------------------------------
// Flash attention v14: split-K=2, launch_bounds(256,2) (compiler free to use
// ~108 VGPR as in verified rounds 11/14 -> no spill). Grid 1024; HW occupancy
// = min(LDS 36.9KB -> 4, VGPR ~108 -> 4) = 4 blocks/CU = 16 waves/CU.
// Partials are EXACT sums (no-max softmax): f32 atomicAdd, 2 contributions
// per location (commutative + 0+x exact -> deterministic).
// ---------------------------------------------------------------------------
__global__ __launch_bounds__(256, 2) void attn_kernel(
    const unsigned short* __restrict__ qb,
    const unsigned short* __restrict__ kb,
    const unsigned short* __restrict__ vbT,
    float* __restrict__ ctx32,
    float* __restrict__ l32)
{
    __shared__ unsigned short Ks[2][64][72];  // [buf][key][stored d]
    __shared__ unsigned short Vt[2][64][72];  // [buf][d][stored key]

    const int tid  = threadIdx.x;
    const int lane = tid & 63;
    const int wave = tid >> 6;
    const int g    = lane >> 4;
    const int lq   = lane & 15;
    // XCD swizzle (bijective on 1024): wg = split*512 + qt*32 + (bh&3)*8 + (bh>>2)
    const int wg    = blockIdx.x + 16 * blockIdx.y + 512 * blockIdx.z;  // 0..1023
    const int bh    = (wg & 7) * 4 + ((wg >> 3) & 3);                   // 0..31
    const int rest  = wg >> 5;                                          // 0..31
    const int qt    = rest & 15;                                        // 0..15
    const int split = rest >> 4;                                        // 0..1
    const int b = bh >> 4, h = bh & 15;
    const int qw = qt * 128 + wave * 32;

    const size_t kvoff = ((size_t)b * 2048) * 1024 + (size_t)h * 64
                       + (size_t)split * 1024 * 1024;   // key offset 1024 rows

    // Q fragments: stored cols [32hf + 8g .. +7], single uint4 each; 2 q-frags
    F8 qf[2][2];
#pragma unroll
    for (int qi = 0; qi < 2; qi++) {
        const size_t qoff = ((size_t)(b * 2048 + qw + qi * 16 + lq)) * 1024 + h * 64;
        qf[qi][0].q = *(const uint4*)(qb + qoff + 8 * g);
        qf[qi][1].q = *(const uint4*)(qb + qoff + 32 + 8 * g);
    }

    const int sr = tid >> 3, sc8 = tid & 7;
    const unsigned short* kbase  = kb + kvoff + (size_t)sr * 1024 + sc8 * 8;
    const unsigned short* vtbase = vbT + ((size_t)bh * 64 + sr) * 2048
                                 + split * 1024 + sc8 * 8;

    uint4 kx0, kx1, vx0, vx1;
#define LOADW(KW) do { \
        const unsigned short* kp = kbase + (size_t)(KW) * 1024; \
        const unsigned short* vp = vtbase + (KW); \
        kx0 = *(const uint4*)kp;  kx1 = *(const uint4*)(kp + 32 * 1024); \
        vx0 = *(const uint4*)vp;  vx1 = *(const uint4*)(vp + 32 * 2048); \
    } while (0)
#define WRITEW(BUF) do { \
        *(uint4*)&Ks[BUF][sr][sc8 * 8]      = kx0; \
        *(uint4*)&Ks[BUF][sr + 32][sc8 * 8] = kx1; \
        *(uint4*)&Vt[BUF][sr][sc8 * 8]      = vx0; \
        *(uint4*)&Vt[BUF][sr + 32][sc8 * 8] = vx1; \
    } while (0)

    float lrun0 = 0.f, lrun1 = 0.f;
    f32x4 acc[4][2];
#pragma unroll
    for (int db = 0; db < 4; db++) {
        acc[db][0] = (f32x4){0.f, 0.f, 0.f, 0.f};
        acc[db][1] = (f32x4){0.f, 0.f, 0.f, 0.f};
    }

    const float SE = 0.03125f * LOG2E;

#define QKSM(CURN, PF) do { \
        _Pragma("unroll") \
        for (int kbi = 0; kbi < 4; kbi++) { \
            const unsigned short* kr = &Ks[CURN][kbi * 16 + lq][0]; \
            F8 kf0, kf1; \
            kf0.q = *(const uint4*)(kr + 8 * g); \
            kf1.q = *(const uint4*)(kr + 32 + 8 * g); \
            f32x4 st0 = (f32x4){0.f, 0.f, 0.f, 0.f}; \
            f32x4 st1 = (f32x4){0.f, 0.f, 0.f, 0.f}; \
            st0 = MFMA16(kf0.v, qf[0][0].v, st0); \
            st0 = MFMA16(kf1.v, qf[0][1].v, st0); \
            st1 = MFMA16(kf0.v, qf[1][0].v, st1); \
            st1 = MFMA16(kf1.v, qf[1][1].v, st1); \
            float a0 = fexp2(st0[0] * SE), a1 = fexp2(st0[1] * SE); \
            float a2 = fexp2(st0[2] * SE), a3 = fexp2(st0[3] * SE); \
            float b0 = fexp2(st1[0] * SE), b1 = fexp2(st1[1] * SE); \
            float b2 = fexp2(st1[2] * SE), b3 = fexp2(st1[3] * SE); \
            lrun0 += (a0 + a1) + (a2 + a3); \
            lrun1 += (b0 + b1) + (b2 + b3); \
            unsigned wa0, wa1, wb0, wb1; \
            asm("v_cvt_pk_bf16_f32 %0, %1, %2" : "=v"(wa0) : "v"(a0), "v"(a1)); \
            asm("v_cvt_pk_bf16_f32 %0, %1, %2" : "=v"(wa1) : "v"(a2), "v"(a3)); \
            asm("v_cvt_pk_bf16_f32 %0, %1, %2" : "=v"(wb0) : "v"(b0), "v"(b1)); \
            asm("v_cvt_pk_bf16_f32 %0, %1, %2" : "=v"(wb1) : "v"(b2), "v"(b3)); \
            PF[0][kbi >> 1].u32[(kbi & 1) * 2 + 0] = wa0; \
            PF[0][kbi >> 1].u32[(kbi & 1) * 2 + 1] = wa1; \
            PF[1][kbi >> 1].u32[(kbi & 1) * 2 + 0] = wb0; \
            PF[1][kbi >> 1].u32[(kbi & 1) * 2 + 1] = wb1; \
        } \
    } while (0)

#define PVSTEP(CURN, PF) do { \
        _Pragma("unroll") \
        for (int kg = 0; kg < 2; kg++) { \
            F8 vf0, vf1, vf2, vf3; \
            vf0.q = *(const uint4*)(&Vt[CURN][ 0 + lq][kg * 32] + 8 * g); \
            vf1.q = *(const uint4*)(&Vt[CURN][16 + lq][kg * 32] + 8 * g); \
            vf2.q = *(const uint4*)(&Vt[CURN][32 + lq][kg * 32] + 8 * g); \
            vf3.q = *(const uint4*)(&Vt[CURN][48 + lq][kg * 32] + 8 * g); \
            __builtin_amdgcn_s_setprio(1); \
            acc[0][0] = MFMA16(vf0.v, PF[0][kg].v, acc[0][0]); \
            acc[1][0] = MFMA16(vf1.v, PF[0][kg].v, acc[1][0]); \
            acc[2][0] = MFMA16(vf2.v, PF[0][kg].v, acc[2][0]); \
            acc[3][0] = MFMA16(vf3.v, PF[0][kg].v, acc[3][0]); \
            acc[0][1] = MFMA16(vf0.v, PF[1][kg].v, acc[0][1]); \
            acc[1][1] = MFMA16(vf1.v, PF[1][kg].v, acc[1][1]); \
            acc[2][1] = MFMA16(vf2.v, PF[1][kg].v, acc[2][1]); \
            acc[3][1] = MFMA16(vf3.v, PF[1][kg].v, acc[3][1]); \
            __builtin_amdgcn_s_setprio(0); \
        } \
    } while (0)

    F8 pfA[2][2], pfB[2][2];

    // prologue: stage w0, compute P(0); stage w1  (16 windows this split)
    LOADW(0);
    WRITEW(0);
    __syncthreads();
    QKSM(0, pfA);
    LOADW(64);
    WRITEW(1);
    __syncthreads();

#define WBODY(CUR, T, PF_CUR, PF_NXT) do { \
        if ((T) + 2 < 16) LOADW(((T) + 2) * 64); \
        if ((T) + 1 < 16) QKSM((CUR) ^ 1, PF_NXT); \
        PVSTEP(CUR, PF_CUR); \
        __syncthreads(); \
        if ((T) + 2 < 16) WRITEW(CUR); \
        __syncthreads(); \
    } while (0)

    for (int t = 0; t < 16; t += 2) {
        WBODY(0, t,     pfA, pfB);
        WBODY(1, t + 1, pfB, pfA);
    }

    // epilogue: reduce l across g-groups; atomically accumulate partials.
    lrun0 += __shfl_xor(lrun0, 16);
    lrun0 += __shfl_xor(lrun0, 32);
    lrun1 += __shfl_xor(lrun1, 16);
    lrun1 += __shfl_xor(lrun1, 32);
    if (lane < 16) {
        atomicAdd(&l32[(size_t)bh * 2048 + qw + lane], lrun0);
        atomicAdd(&l32[(size_t)bh * 2048 + qw + 16 + lane], lrun1);
    }
#pragma unroll
    for (int qi = 0; qi < 2; qi++) {
        const size_t crow = ((size_t)(b * 2048 + qw + qi * 16 + lq)) * 1024 + h * 64;
#pragma unroll
        for (int db = 0; db < 4; db++)
#pragma unroll
            for (int r = 0; r < 4; r++)
                atomicAdd(&ctx32[crow + db * 16 + g * 4 + r], acc[db][qi][r]);
    }
#undef LOADW
#undef WRITEW
#undef QKSM
#undef PVSTEP
#undef WBODY
}

// ---------------------------------------------------------------------------
// Combine: ctx[token][col] = bf16( ctx32[token][col] / l32[bh][q] ).
// ---------------------------------------------------------------------------
__global__ __launch_bounds__(256) void combine_kernel(
    const float* __restrict__ ctx32, const float* __restrict__ l32,
    unsigned short* __restrict__ ctx)
{
    const int token = blockIdx.x;               // 0..4095
    const int col   = threadIdx.x * 4;          // 0..1020
    const int h     = col >> 6;
    const int bh    = (token >> 11) * 16 + h;
    const float l   = l32[(size_t)bh * 2048 + (token & 2047)];
    const float inv = 1.f / l;
    const float4 a  = *(const float4*)(ctx32 + (size_t)token * 1024 + col);
    ushort4 o;
    o.x = f2b(a.x * inv); o.y = f2b(a.y * inv);
    o.z = f2b(a.z * inv); o.w = f2b(a.w * inv);
    *(ushort4*)(ctx + (size_t)token * 1024 + col) = o;
}

// ---------------------------------------------------------------------------
extern "C" void kernel_launch(void* const* d_in, const int* in_sizes, int n_in,
                              void* d_out, int out_size, void* d_ws, size_t ws_size,
                              hipStream_t stream) {
    const float* V  = (const float*)d_in[0];
    const float* Q  = (const float*)d_in[1];
    const float* K  = (const float*)d_in[2];
    const float* Wq = (const float*)d_in[3];
    const float* bq = (const float*)d_in[4];
    const float* Wk = (const float*)d_in[5];
    const float* bk = (const float*)d_in[6];
    const float* Wv = (const float*)d_in[7];
    const float* bv = (const float*)d_in[8];
    const float* Wo = (const float*)d_in[9];
    const float* bo = (const float*)d_in[10];

    const size_t M4 = (size_t)4096 * 1024;
    const size_t M1 = (size_t)1024 * 1024;
    unsigned short* qc  = (unsigned short*)d_ws;
    unsigned short* kc  = qc + M4;
    unsigned short* vc  = kc + M4;
    unsigned short* wtq = vc + M4;
    unsigned short* wtk = wtq + M1;
    unsigned short* wtv = wtk + M1;
    unsigned short* wto = wtv + M1;
    unsigned short* qb  = wto + M1;
    unsigned short* kb  = qb + M4;
    unsigned short* vb  = kb + M4;
    unsigned short* ctx = vb + M4;
    unsigned short* vbT = qc;            // alias: qc dead after proj_kernel
    float* ctx32 = (float*)kc;           // alias: kc+vc (16MB) dead after proj
    float* l32   = (float*)wtq;          // alias: wtq (2MB) dead after proj

    prep_kernel<<<dim3(4096, 1, 4), 256, 0, stream>>>(
        Q, K, V, Wq, Wk, Wv, Wo, qc, kc, vc, wtq, wtk, wtv, wto);
    proj_kernel<<<dim3(32, 8, 3), 256, 0, stream>>>(
        qc, kc, vc, wtq, wtk, wtv, bq, bk, bv, qb, kb, vb);
    transpose_v_kernel<<<dim3(32, 32), 256, 0, stream>>>(vb, vbT);
    hipMemsetAsync(ctx32, 0, M4 * sizeof(float), stream);
    hipMemsetAsync(l32, 0, (size_t)32 * 2048 * sizeof(float), stream);
    attn_kernel<<<dim3(16, 32, 2), 256, 0, stream>>>(qb, kb, vbT, ctx32, l32);
    combine_kernel<<<dim3(4096), 256, 0, stream>>>(ctx32, l32, ctx);
    out_proj_kernel<<<dim3(32, 8), 256, 0, stream>>>(ctx, wto, bo, (float*)d_out);
}

// Round 17
// 117.082 us; speedup vs baseline: 3.0097x; 1.8660x over previous
//
#include <hip/hip_runtime.h>
#include <hip/hip_bf16.h>
#include <stdint.h>

// B=2, S=2048, D=1024, H=16, dh=64. All matrices row-major.
// ws (bf16 elems): qc kc vc (4M each) | wtq wtk wtv wto (1M each) |
//   qb kb vb ctx (4M each) = 64 MB.
// qb/kb stored with within-head d-permutation sigma (QK^T invariant).
// V projection (z==2) writes DIRECTLY in vbT layout into vb's slot:
//   vb[(b*16+h)*64 + d][tau(key)] with tau within 32-key groups
//   (fuses the old transpose_v kernel into the proj epilogue).
// == Round 14 (verified, 120.8us) + transpose_v fused into proj. ==

typedef __attribute__((ext_vector_type(8))) short bf16x8;
typedef __attribute__((ext_vector_type(4))) float f32x4;

#define LOG2E 1.44269504088896340736f

union F8 {
    uint64_t u64[2];
    unsigned u32[4];
    unsigned short s[8];
    bf16x8 v;
    uint4 q;
};

__device__ __forceinline__ unsigned short f2b(float f) {
    union { float f; unsigned u; } x; x.f = f;
    unsigned r = x.u + 0x7FFF + ((x.u >> 16) & 1);  // RNE
    return (unsigned short)(r >> 16);
}

// Hardware exp2 (verified round 10: bit-identical output, -22% VALUBusy).
#if __has_builtin(__builtin_amdgcn_exp2f)
__device__ __forceinline__ float fexp2(float x) { return __builtin_amdgcn_exp2f(x); }
#else
extern "C" __device__ float __ocml_native_exp2_f32(float);
__device__ __forceinline__ float fexp2(float x) { return __ocml_native_exp2_f32(x); }
#endif

__device__ __forceinline__ void gload_lds16(const void* g, void* l) {
    __builtin_amdgcn_global_load_lds(
        (const __attribute__((address_space(1))) void*)g,
        (__attribute__((address_space(3))) void*)l, 16, 0, 0);
}

#define MFMA16(A, B, C) __builtin_amdgcn_mfma_f32_16x16x32_bf16(A, B, C, 0, 0, 0)

// ---------------------------------------------------------------------------
// Fused prep: z<3 -> fp32->bf16 convert of Q/K/V (4096 blocks each);
// z==3 -> Wt[n][k]=bf16(W[k][n]) for 4 weights (1024 blocks, rest exit).
// ---------------------------------------------------------------------------
__global__ __launch_bounds__(256) void prep_kernel(
    const float* __restrict__ Q, const float* __restrict__ K, const float* __restrict__ V,
    const float* __restrict__ Wq, const float* __restrict__ Wk,
    const float* __restrict__ Wv, const float* __restrict__ Wo,
    unsigned short* __restrict__ qc, unsigned short* __restrict__ kc,
    unsigned short* __restrict__ vc,
    unsigned short* __restrict__ wtq, unsigned short* __restrict__ wtk,
    unsigned short* __restrict__ wtv, unsigned short* __restrict__ wto)
{
    __shared__ unsigned short T[64][68];
    const int z = blockIdx.z;
    if (z < 3) {
        const float* src = (z == 0) ? Q : ((z == 1) ? K : V);
        unsigned short* dst = (z == 0) ? qc : ((z == 1) ? kc : vc);
        const size_t i = ((size_t)blockIdx.x * 256 + threadIdx.x) * 4;
        const float4 v = *(const float4*)(src + i);
        ushort4 o;
        o.x = f2b(v.x); o.y = f2b(v.y); o.z = f2b(v.z); o.w = f2b(v.w);
        *(ushort4*)(dst + i) = o;
        return;
    }
    if (blockIdx.x >= 1024) return;   // uniform early exit (whole block)
    const int w  = blockIdx.x >> 8;          // weight id 0..3
    const int kt = blockIdx.x & 15;          // k-tile
    const int nt = (blockIdx.x >> 4) & 15;   // n-tile
    const float* W = (w == 0) ? Wq : ((w == 1) ? Wk : ((w == 2) ? Wv : Wo));
    unsigned short* Wt = (w == 0) ? wtq : ((w == 1) ? wtk : ((w == 2) ? wtv : wto));

    const int t = threadIdx.x;
    const int r = t >> 2, cg = t & 3;
    const int k0 = kt * 64, n0 = nt * 64;

#pragma unroll
    for (int i = 0; i < 4; i++) {
        const float4 v = *(const float4*)(W + (size_t)(k0 + r) * 1024 + n0 + cg * 16 + i * 4);
        T[r][cg * 16 + i * 4 + 0] = f2b(v.x);
        T[r][cg * 16 + i * 4 + 1] = f2b(v.y);
        T[r][cg * 16 + i * 4 + 2] = f2b(v.z);
        T[r][cg * 16 + i * 4 + 3] = f2b(v.w);
    }
    __syncthreads();
#pragma unroll
    for (int i = 0; i < 4; i++) {
        ushort4 o;
        o.x = T[cg * 16 + i * 4 + 0][r];
        o.y = T[cg * 16 + i * 4 + 1][r];
        o.z = T[cg * 16 + i * 4 + 2][r];
        o.w = T[cg * 16 + i * 4 + 3][r];
        *(ushort4*)(Wt + (size_t)(n0 + r) * 1024 + k0 + cg * 16 + i * 4) = o;
    }
}

// ---------------------------------------------------------------------------
// m97-style bf16 GEMM. perm (runtime, block-uniform): sigma d-perm for qb/kb.
// vmode (runtime, block-uniform): write output directly in vbT layout
// (row = (b*16+h)*64 + d, col = tau(key)), fusing the old V-transpose.
// Single instantiation per kernel -> one 32KB LDS allocation.
// ---------------------------------------------------------------------------
template<bool OUT_F32>
__device__ __forceinline__ void gemm_bf16_body(
    const unsigned short* __restrict__ A, const unsigned short* __restrict__ Bt,
    const float* __restrict__ bias, void* __restrict__ outv,
    const bool perm, const bool vmode)
{
    __shared__ unsigned short As[2][128][32];
    __shared__ unsigned short Bs[2][128][32];

    const int tid  = threadIdx.x;
    const int lane = tid & 63;
    const int wid  = tid >> 6;
    const int g    = lane >> 4;
    const int lq   = lane & 15;
    const int wm   = wid >> 1;
    const int wn   = wid & 1;
    const int Mbase = blockIdx.x * 128;
    const int Nbase = blockIdx.y * 128;

    const int srow = lane >> 2;
    const int scol = (lane & 3) * 8;

#define STAGE(BF, KT) do { \
        _Pragma("unroll") \
        for (int c = 0; c < 2; c++) { \
            const int ch = wid * 2 + c; \
            gload_lds16(A  + (size_t)(Mbase + ch * 16 + srow) * 1024 + (KT) + scol, \
                        &As[BF][ch * 16][0]); \
            gload_lds16(Bt + (size_t)(Nbase + ch * 16 + srow) * 1024 + (KT) + scol, \
                        &Bs[BF][ch * 16][0]); \
        } \
    } while (0)

    f32x4 acc[4][4];
#pragma unroll
    for (int i = 0; i < 4; i++)
#pragma unroll
        for (int j = 0; j < 4; j++)
            acc[i][j] = (f32x4){0.f, 0.f, 0.f, 0.f};

    STAGE(0, 0);
    __syncthreads();

    int cur = 0;
    for (int kt = 0; kt < 1024; kt += 32) {
        if (kt < 992) STAGE(cur ^ 1, kt + 32);

        F8 af[4], bfr[4];
#pragma unroll
        for (int mi = 0; mi < 4; mi++)
            af[mi].v = *(const bf16x8*)&As[cur][wm * 64 + mi * 16 + lq][8 * g];
#pragma unroll
        for (int ni = 0; ni < 4; ni++)
            bfr[ni].v = *(const bf16x8*)&Bs[cur][wn * 64 + ni * 16 + lq][8 * g];

        __builtin_amdgcn_s_setprio(1);
#pragma unroll
        for (int mi = 0; mi < 4; mi++)
#pragma unroll
            for (int ni = 0; ni < 4; ni++)
                acc[mi][ni] = MFMA16(af[mi].v, bfr[ni].v, acc[mi][ni]);
        __builtin_amdgcn_s_setprio(0);

        __syncthreads();
        cur ^= 1;
    }

#pragma unroll
    for (int mi = 0; mi < 4; mi++) {
#pragma unroll
        for (int ni = 0; ni < 4; ni++) {
            const int d_nat = ni * 16 + lq;            // 0..63 within head
            const float bb = bias[Nbase + wn * 64 + d_nat];
            if (vmode) {
                // direct vbT write: row=(b*16+h)*64+d, col=tau(key)
                const int mg0 = Mbase + wm * 64 + mi * 16 + g * 4;  // r=0
                const int b   = mg0 >> 11;
                const int key = mg0 & 2047;
                const int h   = (Nbase >> 6) + wn;
                const int row = (b * 16 + h) * 64 + d_nat;
                const int col = (key & ~31) + 8 * ((key >> 2) & 3)
                              + 4 * ((key >> 4) & 1);
                F8 o;
                o.s[0] = f2b(acc[mi][ni][0] + bb);
                o.s[1] = f2b(acc[mi][ni][1] + bb);
                o.s[2] = f2b(acc[mi][ni][2] + bb);
                o.s[3] = f2b(acc[mi][ni][3] + bb);
                *(uint64_t*)((unsigned short*)outv + (size_t)row * 2048 + col) = o.u64[0];
            } else {
                const int d_prm = (ni >> 1) * 32 + (lq >> 2) * 8 + (ni & 1) * 4 + (lq & 3);
                const int ng = Nbase + wn * 64 + (perm ? d_prm : d_nat);
#pragma unroll
                for (int r = 0; r < 4; r++) {
                    int mg = Mbase + wm * 64 + mi * 16 + g * 4 + r;
                    float val = acc[mi][ni][r] + bb;
                    if (OUT_F32)
                        ((float*)outv)[(size_t)mg * 1024 + ng] = val;
                    else
                        ((unsigned short*)outv)[(size_t)mg * 1024 + ng] = f2b(val);
                }
            }
        }
    }
#undef STAGE
}

__global__ __launch_bounds__(256) void proj_kernel(
    const unsigned short* __restrict__ qc, const unsigned short* __restrict__ kc,
    const unsigned short* __restrict__ vc,
    const unsigned short* __restrict__ wtq, const unsigned short* __restrict__ wtk,
    const unsigned short* __restrict__ wtv,
    const float* __restrict__ bq, const float* __restrict__ bk,
    const float* __restrict__ bv,
    unsigned short* qb, unsigned short* kb, unsigned short* vb)
{
    const int z = blockIdx.z;
    const unsigned short* A  = (z == 0) ? qc : ((z == 1) ? kc : vc);
    const unsigned short* Bt = (z == 0) ? wtq : ((z == 1) ? wtk : wtv);
    const float* bias = (z == 0) ? bq : ((z == 1) ? bk : bv);
    unsigned short* out = (z == 0) ? qb : ((z == 1) ? kb : vb);
    gemm_bf16_body<false>(A, Bt, bias, out, z != 2, z == 2);
}

__global__ __launch_bounds__(256) void out_proj_kernel(
    const unsigned short* __restrict__ ctx, const unsigned short* __restrict__ wto,
    const float* __restrict__ bo, float* __restrict__ out)
{
    gemm_bf16_body<true>(ctx, wto, bo, out, false, false);
}

// ---------------------------------------------------------------------------
// Flash attention (round-14 verified body): 3-buffer LDS rotation, one
// barrier per window. QBLK=128 (4 waves x 32 q, 2 q-frags), KVBLK=64,
// hardware exp2, XCD swizzle. vbT = vb buffer (written by proj z==2).
// ---------------------------------------------------------------------------
__global__ __launch_bounds__(256, 2) void attn_kernel(
    const unsigned short* __restrict__ qb,
    const unsigned short* __restrict__ kb,
    const unsigned short* __restrict__ vbT,
    unsigned short* __restrict__ ctx)
{
    __shared__ unsigned short Ks[3][64][72];  // [buf][key][stored d]
    __shared__ unsigned short Vt[3][64][72];  // [buf][d][stored key]

    const int tid  = threadIdx.x;
    const int lane = tid & 63;
    const int wave = tid >> 6;
    const int g    = lane >> 4;
    const int lq   = lane & 15;
    // XCD swizzle (bijective on 512): wg = qt*32 + (bh&3)*8 + (bh>>2)
    const int wg   = blockIdx.x + 16 * blockIdx.y;           // 0..511
    const int bh   = (wg & 7) * 4 + ((wg >> 3) & 3);         // 0..31
    const int qt   = wg >> 5;                                 // 0..15
    const int b = bh >> 4, h = bh & 15;
    const int qw = qt * 128 + wave * 32;                      // wave's 32 queries

    const size_t kvoff = ((size_t)b * 2048) * 1024 + (size_t)h * 64;

    // Q fragments: stored cols [32hf + 8g .. +7], single uint4 each; 2 q-frags
    F8 qf[2][2];
#pragma unroll
    for (int qi = 0; qi < 2; qi++) {
        const size_t qoff = ((size_t)(b * 2048 + qw + qi * 16 + lq)) * 1024 + h * 64;
        qf[qi][0].q = *(const uint4*)(qb + qoff + 8 * g);
        qf[qi][1].q = *(const uint4*)(qb + qoff + 32 + 8 * g);
    }

    const int sr = tid >> 3, sc8 = tid & 7;
    const unsigned short* kbase  = kb + kvoff + (size_t)sr * 1024 + sc8 * 8;
    const unsigned short* vtbase = vbT + ((size_t)bh * 64 + sr) * 2048 + sc8 * 8;

    uint4 kx0, kx1, vx0, vx1;
#define LOADW(KW) do { \
        const unsigned short* kp = kbase + (size_t)(KW) * 1024; \
        const unsigned short* vp = vtbase + (KW); \
        kx0 = *(const uint4*)kp;  kx1 = *(const uint4*)(kp + 32 * 1024); \
        vx0 = *(const uint4*)vp;  vx1 = *(const uint4*)(vp + 32 * 2048); \
    } while (0)
#define WRITEW(BUF) do { \
        *(uint4*)&Ks[BUF][sr][sc8 * 8]      = kx0; \
        *(uint4*)&Ks[BUF][sr + 32][sc8 * 8] = kx1; \
        *(uint4*)&Vt[BUF][sr][sc8 * 8]      = vx0; \
        *(uint4*)&Vt[BUF][sr + 32][sc8 * 8] = vx1; \
    } while (0)

    float lrun0 = 0.f, lrun1 = 0.f;
    f32x4 acc[4][2];
#pragma unroll
    for (int db = 0; db < 4; db++) {
        acc[db][0] = (f32x4){0.f, 0.f, 0.f, 0.f};
        acc[db][1] = (f32x4){0.f, 0.f, 0.f, 0.f};
    }

    const float SE = 0.03125f * LOG2E;

    // QK^T on buffer CURN -> exp2 -> packed bf16 P (2 q-frags, shared K reads)
#define QKSM(CURN, PF) do { \
        _Pragma("unroll") \
        for (int kbi = 0; kbi < 4; kbi++) { \
            const unsigned short* kr = &Ks[CURN][kbi * 16 + lq][0]; \
            F8 kf0, kf1; \
            kf0.q = *(const uint4*)(kr + 8 * g); \
            kf1.q = *(const uint4*)(kr + 32 + 8 * g); \
            f32x4 st0 = (f32x4){0.f, 0.f, 0.f, 0.f}; \
            f32x4 st1 = (f32x4){0.f, 0.f, 0.f, 0.f}; \
            st0 = MFMA16(kf0.v, qf[0][0].v, st0); \
            st0 = MFMA16(kf1.v, qf[0][1].v, st0); \
            st1 = MFMA16(kf0.v, qf[1][0].v, st1); \
            st1 = MFMA16(kf1.v, qf[1][1].v, st1); \
            float a0 = fexp2(st0[0] * SE), a1 = fexp2(st0[1] * SE); \
            float a2 = fexp2(st0[2] * SE), a3 = fexp2(st0[3] * SE); \
            float b0 = fexp2(st1[0] * SE), b1 = fexp2(st1[1] * SE); \
            float b2 = fexp2(st1[2] * SE), b3 = fexp2(st1[3] * SE); \
            lrun0 += (a0 + a1) + (a2 + a3); \
            lrun1 += (b0 + b1) + (b2 + b3); \
            unsigned wa0, wa1, wb0, wb1; \
            asm("v_cvt_pk_bf16_f32 %0, %1, %2" : "=v"(wa0) : "v"(a0), "v"(a1)); \
            asm("v_cvt_pk_bf16_f32 %0, %1, %2" : "=v"(wa1) : "v"(a2), "v"(a3)); \
            asm("v_cvt_pk_bf16_f32 %0, %1, %2" : "=v"(wb0) : "v"(b0), "v"(b1)); \
            asm("v_cvt_pk_bf16_f32 %0, %1, %2" : "=v"(wb1) : "v"(b2), "v"(b3)); \
            PF[0][kbi >> 1].u32[(kbi & 1) * 2 + 0] = wa0; \
            PF[0][kbi >> 1].u32[(kbi & 1) * 2 + 1] = wa1; \
            PF[1][kbi >> 1].u32[(kbi & 1) * 2 + 0] = wb0; \
            PF[1][kbi >> 1].u32[(kbi & 1) * 2 + 1] = wb1; \
        } \
    } while (0)

    // PV on buffer CURN: V-frag reads shared across both q-frags
#define PVSTEP(CURN, PF) do { \
        _Pragma("unroll") \
        for (int kg = 0; kg < 2; kg++) { \
            F8 vf0, vf1, vf2, vf3; \
            vf0.q = *(const uint4*)(&Vt[CURN][ 0 + lq][kg * 32] + 8 * g); \
            vf1.q = *(const uint4*)(&Vt[CURN][16 + lq][kg * 32] + 8 * g); \
            vf2.q = *(const uint4*)(&Vt[CURN][32 + lq][kg * 32] + 8 * g); \
            vf3.q = *(const uint4*)(&Vt[CURN][48 + lq][kg * 32] + 8 * g); \
            __builtin_amdgcn_s_setprio(1); \
            acc[0][0] = MFMA16(vf0.v, PF[0][kg].v, acc[0][0]); \
            acc[1][0] = MFMA16(vf1.v, PF[0][kg].v, acc[1][0]); \
            acc[2][0] = MFMA16(vf2.v, PF[0][kg].v, acc[2][0]); \
            acc[3][0] = MFMA16(vf3.v, PF[0][kg].v, acc[3][0]); \
            acc[0][1] = MFMA16(vf0.v, PF[1][kg].v, acc[0][1]); \
            acc[1][1] = MFMA16(vf1.v, PF[1][kg].v, acc[1][1]); \
            acc[2][1] = MFMA16(vf2.v, PF[1][kg].v, acc[2][1]); \
            acc[3][1] = MFMA16(vf3.v, PF[1][kg].v, acc[3][1]); \
            __builtin_amdgcn_s_setprio(0); \
        } \
    } while (0)

    F8 pfA[2][2], pfB[2][2];

    // prologue: fill buf0 + buf1, compute P(0) into pfA
    LOADW(0);
    WRITEW(0);
    LOADW(64);
    __syncthreads();          // buf0 ready
    QKSM(0, pfA);
    WRITEW(1);
    __syncthreads();          // buf1 ready

    // window T: PV reads buf T%3, QK(T+1) reads (T+1)%3, write (T+2)%3.
#define WBODY(BCUR, BNXT, BWR, T, PF_CUR, PF_NXT) do { \
        if ((T) + 2 < 32) LOADW(((T) + 2) * 64); \
        if ((T) + 1 < 32) QKSM(BNXT, PF_NXT); \
        PVSTEP(BCUR, PF_CUR); \
        if ((T) + 2 < 32) WRITEW(BWR); \
        __syncthreads(); \
    } while (0)

    for (int t = 0; t < 30; t += 6) {
        WBODY(0, 1, 2, t + 0, pfA, pfB);
        WBODY(1, 2, 0, t + 1, pfB, pfA);
        WBODY(2, 0, 1, t + 2, pfA, pfB);
        WBODY(0, 1, 2, t + 3, pfB, pfA);
        WBODY(1, 2, 0, t + 4, pfA, pfB);
        WBODY(2, 0, 1, t + 5, pfB, pfA);
    }
    WBODY(0, 1, 2, 30, pfA, pfB);   // window 30 (computes P(31) into pfB)
    WBODY(1, 2, 0, 31, pfB, pfA);   // window 31 (PV only)

    // final l reduction (4 g-groups per query) + store ctx^T, per q-frag
    lrun0 += __shfl_xor(lrun0, 16);
    lrun0 += __shfl_xor(lrun0, 32);
    lrun1 += __shfl_xor(lrun1, 16);
    lrun1 += __shfl_xor(lrun1, 32);
#pragma unroll
    for (int qi = 0; qi < 2; qi++) {
        const float inv = 1.f / (qi ? lrun1 : lrun0);
        const size_t crow = ((size_t)(b * 2048 + qw + qi * 16 + lq)) * 1024 + h * 64;
#pragma unroll
        for (int db = 0; db < 4; db++)
#pragma unroll
            for (int r = 0; r < 4; r++)
                ctx[crow + db * 16 + g * 4 + r] = f2b(acc[db][qi][r] * inv);
    }
#undef LOADW
#undef WRITEW
#undef QKSM
#undef PVSTEP
#undef WBODY
}

// ---------------------------------------------------------------------------
extern "C" void kernel_launch(void* const* d_in, const int* in_sizes, int n_in,
                              void* d_out, int out_size, void* d_ws, size_t ws_size,
                              hipStream_t stream) {
    const float* V  = (const float*)d_in[0];
    const float* Q  = (const float*)d_in[1];
    const float* K  = (const float*)d_in[2];
    const float* Wq = (const float*)d_in[3];
    const float* bq = (const float*)d_in[4];
    const float* Wk = (const float*)d_in[5];
    const float* bk = (const float*)d_in[6];
    const float* Wv = (const float*)d_in[7];
    const float* bv = (const float*)d_in[8];
    const float* Wo = (const float*)d_in[9];
    const float* bo = (const float*)d_in[10];

    const size_t M4 = (size_t)4096 * 1024;
    const size_t M1 = (size_t)1024 * 1024;
    unsigned short* qc  = (unsigned short*)d_ws;
    unsigned short* kc  = qc + M4;
    unsigned short* vc  = kc + M4;
    unsigned short* wtq = vc + M4;
    unsigned short* wtk = wtq + M1;
    unsigned short* wtv = wtk + M1;
    unsigned short* wto = wtv + M1;
    unsigned short* qb  = wto + M1;
    unsigned short* kb  = qb + M4;
    unsigned short* vb  = kb + M4;   // holds V in vbT layout (written by proj z==2)
    unsigned short* ctx = vb + M4;

    prep_kernel<<<dim3(4096, 1, 4), 256, 0, stream>>>(
        Q, K, V, Wq, Wk, Wv, Wo, qc, kc, vc, wtq, wtk, wtv, wto);
    proj_kernel<<<dim3(32, 8, 3), 256, 0, stream>>>(
        qc, kc, vc, wtq, wtk, wtv, bq, bk, bv, qb, kb, vb);
    attn_kernel<<<dim3(16, 32), 256, 0, stream>>>(qb, kb, vb, ctx);
    out_proj_kernel<<<dim3(32, 8), 256, 0, stream>>>(ctx, wto, bo, (float*)d_out);
}

// Round 19
// 116.731 us; speedup vs baseline: 3.0188x; 1.0030x over previous
//
#include <hip/hip_runtime.h>
#include <hip/hip_bf16.h>
#include <stdint.h>

// B=2, S=2048, D=1024, H=16, dh=64. All matrices row-major.
// ws (bf16 elems): qc kc vc (4M each) | wtq wtk wtv wto (1M each) |
//   qb kb vb ctx (4M each) = 64 MB.
// qb/kb stored with within-head d-permutation sigma (QK^T invariant).
// V projection (z==2) writes DIRECTLY in vbT layout into vb's slot:
//   vb[(b*16+h)*64 + d][tau(key)] with tau within 32-key groups
//   (fuses the old transpose_v kernel into the proj epilogue).
// == Exact revert to Round 17 (verified PASS, 117.1us). Round 18's
//    ones-MFMA l-sum failed (7.3e-3) for reasons outside the arithmetic
//    model (codegen-level suspect); line abandoned per discipline. ==

typedef __attribute__((ext_vector_type(8))) short bf16x8;
typedef __attribute__((ext_vector_type(4))) float f32x4;

#define LOG2E 1.44269504088896340736f

union F8 {
    uint64_t u64[2];
    unsigned u32[4];
    unsigned short s[8];
    bf16x8 v;
    uint4 q;
};

__device__ __forceinline__ unsigned short f2b(float f) {
    union { float f; unsigned u; } x; x.f = f;
    unsigned r = x.u + 0x7FFF + ((x.u >> 16) & 1);  // RNE
    return (unsigned short)(r >> 16);
}

// Hardware exp2 (verified round 10: bit-identical output, -22% VALUBusy).
#if __has_builtin(__builtin_amdgcn_exp2f)
__device__ __forceinline__ float fexp2(float x) { return __builtin_amdgcn_exp2f(x); }
#else
extern "C" __device__ float __ocml_native_exp2_f32(float);
__device__ __forceinline__ float fexp2(float x) { return __ocml_native_exp2_f32(x); }
#endif

__device__ __forceinline__ void gload_lds16(const void* g, void* l) {
    __builtin_amdgcn_global_load_lds(
        (const __attribute__((address_space(1))) void*)g,
        (__attribute__((address_space(3))) void*)l, 16, 0, 0);
}

#define MFMA16(A, B, C) __builtin_amdgcn_mfma_f32_16x16x32_bf16(A, B, C, 0, 0, 0)

// ---------------------------------------------------------------------------
// Fused prep: z<3 -> fp32->bf16 convert of Q/K/V (4096 blocks each);
// z==3 -> Wt[n][k]=bf16(W[k][n]) for 4 weights (1024 blocks, rest exit).
// ---------------------------------------------------------------------------
__global__ __launch_bounds__(256) void prep_kernel(
    const float* __restrict__ Q, const float* __restrict__ K, const float* __restrict__ V,
    const float* __restrict__ Wq, const float* __restrict__ Wk,
    const float* __restrict__ Wv, const float* __restrict__ Wo,
    unsigned short* __restrict__ qc, unsigned short* __restrict__ kc,
    unsigned short* __restrict__ vc,
    unsigned short* __restrict__ wtq, unsigned short* __restrict__ wtk,
    unsigned short* __restrict__ wtv, unsigned short* __restrict__ wto)
{
    __shared__ unsigned short T[64][68];
    const int z = blockIdx.z;
    if (z < 3) {
        const float* src = (z == 0) ? Q : ((z == 1) ? K : V);
        unsigned short* dst = (z == 0) ? qc : ((z == 1) ? kc : vc);
        const size_t i = ((size_t)blockIdx.x * 256 + threadIdx.x) * 4;
        const float4 v = *(const float4*)(src + i);
        ushort4 o;
        o.x = f2b(v.x); o.y = f2b(v.y); o.z = f2b(v.z); o.w = f2b(v.w);
        *(ushort4*)(dst + i) = o;
        return;
    }
    if (blockIdx.x >= 1024) return;   // uniform early exit (whole block)
    const int w  = blockIdx.x >> 8;          // weight id 0..3
    const int kt = blockIdx.x & 15;          // k-tile
    const int nt = (blockIdx.x >> 4) & 15;   // n-tile
    const float* W = (w == 0) ? Wq : ((w == 1) ? Wk : ((w == 2) ? Wv : Wo));
    unsigned short* Wt = (w == 0) ? wtq : ((w == 1) ? wtk : ((w == 2) ? wtv : wto));

    const int t = threadIdx.x;
    const int r = t >> 2, cg = t & 3;
    const int k0 = kt * 64, n0 = nt * 64;

#pragma unroll
    for (int i = 0; i < 4; i++) {
        const float4 v = *(const float4*)(W + (size_t)(k0 + r) * 1024 + n0 + cg * 16 + i * 4);
        T[r][cg * 16 + i * 4 + 0] = f2b(v.x);
        T[r][cg * 16 + i * 4 + 1] = f2b(v.y);
        T[r][cg * 16 + i * 4 + 2] = f2b(v.z);
        T[r][cg * 16 + i * 4 + 3] = f2b(v.w);
    }
    __syncthreads();
#pragma unroll
    for (int i = 0; i < 4; i++) {
        ushort4 o;
        o.x = T[cg * 16 + i * 4 + 0][r];
        o.y = T[cg * 16 + i * 4 + 1][r];
        o.z = T[cg * 16 + i * 4 + 2][r];
        o.w = T[cg * 16 + i * 4 + 3][r];
        *(ushort4*)(Wt + (size_t)(n0 + r) * 1024 + k0 + cg * 16 + i * 4) = o;
    }
}

// ---------------------------------------------------------------------------
// m97-style bf16 GEMM. perm (runtime, block-uniform): sigma d-perm for qb/kb.
// vmode (runtime, block-uniform): write output directly in vbT layout
// (row = (b*16+h)*64 + d, col = tau(key)), fusing the old V-transpose.
// Single instantiation per kernel -> one 32KB LDS allocation.
// ---------------------------------------------------------------------------
template<bool OUT_F32>
__device__ __forceinline__ void gemm_bf16_body(
    const unsigned short* __restrict__ A, const unsigned short* __restrict__ Bt,
    const float* __restrict__ bias, void* __restrict__ outv,
    const bool perm, const bool vmode)
{
    __shared__ unsigned short As[2][128][32];
    __shared__ unsigned short Bs[2][128][32];

    const int tid  = threadIdx.x;
    const int lane = tid & 63;
    const int wid  = tid >> 6;
    const int g    = lane >> 4;
    const int lq   = lane & 15;
    const int wm   = wid >> 1;
    const int wn   = wid & 1;
    const int Mbase = blockIdx.x * 128;
    const int Nbase = blockIdx.y * 128;

    const int srow = lane >> 2;
    const int scol = (lane & 3) * 8;

#define STAGE(BF, KT) do { \
        _Pragma("unroll") \
        for (int c = 0; c < 2; c++) { \
            const int ch = wid * 2 + c; \
            gload_lds16(A  + (size_t)(Mbase + ch * 16 + srow) * 1024 + (KT) + scol, \
                        &As[BF][ch * 16][0]); \
            gload_lds16(Bt + (size_t)(Nbase + ch * 16 + srow) * 1024 + (KT) + scol, \
                        &Bs[BF][ch * 16][0]); \
        } \
    } while (0)

    f32x4 acc[4][4];
#pragma unroll
    for (int i = 0; i < 4; i++)
#pragma unroll
        for (int j = 0; j < 4; j++)
            acc[i][j] = (f32x4){0.f, 0.f, 0.f, 0.f};

    STAGE(0, 0);
    __syncthreads();

    int cur = 0;
    for (int kt = 0; kt < 1024; kt += 32) {
        if (kt < 992) STAGE(cur ^ 1, kt + 32);

        F8 af[4], bfr[4];
#pragma unroll
        for (int mi = 0; mi < 4; mi++)
            af[mi].v = *(const bf16x8*)&As[cur][wm * 64 + mi * 16 + lq][8 * g];
#pragma unroll
        for (int ni = 0; ni < 4; ni++)
            bfr[ni].v = *(const bf16x8*)&Bs[cur][wn * 64 + ni * 16 + lq][8 * g];

        __builtin_amdgcn_s_setprio(1);
#pragma unroll
        for (int mi = 0; mi < 4; mi++)
#pragma unroll
            for (int ni = 0; ni < 4; ni++)
                acc[mi][ni] = MFMA16(af[mi].v, bfr[ni].v, acc[mi][ni]);
        __builtin_amdgcn_s_setprio(0);

        __syncthreads();
        cur ^= 1;
    }

#pragma unroll
    for (int mi = 0; mi < 4; mi++) {
#pragma unroll
        for (int ni = 0; ni < 4; ni++) {
            const int d_nat = ni * 16 + lq;            // 0..63 within head
            const float bb = bias[Nbase + wn * 64 + d_nat];
            if (vmode) {
                // direct vbT write: row=(b*16+h)*64+d, col=tau(key)
                const int mg0 = Mbase + wm * 64 + mi * 16 + g * 4;  // r=0
                const int b   = mg0 >> 11;
                const int key = mg0 & 2047;
                const int h   = (Nbase >> 6) + wn;
                const int row = (b * 16 + h) * 64 + d_nat;
                const int col = (key & ~31) + 8 * ((key >> 2) & 3)
                              + 4 * ((key >> 4) & 1);
                F8 o;
                o.s[0] = f2b(acc[mi][ni][0] + bb);
                o.s[1] = f2b(acc[mi][ni][1] + bb);
                o.s[2] = f2b(acc[mi][ni][2] + bb);
                o.s[3] = f2b(acc[mi][ni][3] + bb);
                *(uint64_t*)((unsigned short*)outv + (size_t)row * 2048 + col) = o.u64[0];
            } else {
                const int d_prm = (ni >> 1) * 32 + (lq >> 2) * 8 + (ni & 1) * 4 + (lq & 3);
                const int ng = Nbase + wn * 64 + (perm ? d_prm : d_nat);
#pragma unroll
                for (int r = 0; r < 4; r++) {
                    int mg = Mbase + wm * 64 + mi * 16 + g * 4 + r;
                    float val = acc[mi][ni][r] + bb;
                    if (OUT_F32)
                        ((float*)outv)[(size_t)mg * 1024 + ng] = val;
                    else
                        ((unsigned short*)outv)[(size_t)mg * 1024 + ng] = f2b(val);
                }
            }
        }
    }
#undef STAGE
}

__global__ __launch_bounds__(256) void proj_kernel(
    const unsigned short* __restrict__ qc, const unsigned short* __restrict__ kc,
    const unsigned short* __restrict__ vc,
    const unsigned short* __restrict__ wtq, const unsigned short* __restrict__ wtk,
    const unsigned short* __restrict__ wtv,
    const float* __restrict__ bq, const float* __restrict__ bk,
    const float* __restrict__ bv,
    unsigned short* qb, unsigned short* kb, unsigned short* vb)
{
    const int z = blockIdx.z;
    const unsigned short* A  = (z == 0) ? qc : ((z == 1) ? kc : vc);
    const unsigned short* Bt = (z == 0) ? wtq : ((z == 1) ? wtk : wtv);
    const float* bias = (z == 0) ? bq : ((z == 1) ? bk : bv);
    unsigned short* out = (z == 0) ? qb : ((z == 1) ? kb : vb);
    gemm_bf16_body<false>(A, Bt, bias, out, z != 2, z == 2);
}

__global__ __launch_bounds__(256) void out_proj_kernel(
    const unsigned short* __restrict__ ctx, const unsigned short* __restrict__ wto,
    const float* __restrict__ bo, float* __restrict__ out)
{
    gemm_bf16_body<true>(ctx, wto, bo, out, false, false);
}

// ---------------------------------------------------------------------------
// Flash attention (round-14 verified body): 3-buffer LDS rotation, one
// barrier per window. QBLK=128 (4 waves x 32 q, 2 q-frags), KVBLK=64,
// hardware exp2, XCD swizzle. vbT = vb buffer (written by proj z==2).
// ---------------------------------------------------------------------------
__global__ __launch_bounds__(256, 2) void attn_kernel(
    const unsigned short* __restrict__ qb,
    const unsigned short* __restrict__ kb,
    const unsigned short* __restrict__ vbT,
    unsigned short* __restrict__ ctx)
{
    __shared__ unsigned short Ks[3][64][72];  // [buf][key][stored d]
    __shared__ unsigned short Vt[3][64][72];  // [buf][d][stored key]

    const int tid  = threadIdx.x;
    const int lane = tid & 63;
    const int wave = tid >> 6;
    const int g    = lane >> 4;
    const int lq   = lane & 15;
    // XCD swizzle (bijective on 512): wg = qt*32 + (bh&3)*8 + (bh>>2)
    const int wg   = blockIdx.x + 16 * blockIdx.y;           // 0..511
    const int bh   = (wg & 7) * 4 + ((wg >> 3) & 3);         // 0..31
    const int qt   = wg >> 5;                                 // 0..15
    const int b = bh >> 4, h = bh & 15;
    const int qw = qt * 128 + wave * 32;                      // wave's 32 queries

    const size_t kvoff = ((size_t)b * 2048) * 1024 + (size_t)h * 64;

    // Q fragments: stored cols [32hf + 8g .. +7], single uint4 each; 2 q-frags
    F8 qf[2][2];
#pragma unroll
    for (int qi = 0; qi < 2; qi++) {
        const size_t qoff = ((size_t)(b * 2048 + qw + qi * 16 + lq)) * 1024 + h * 64;
        qf[qi][0].q = *(const uint4*)(qb + qoff + 8 * g);
        qf[qi][1].q = *(const uint4*)(qb + qoff + 32 + 8 * g);
    }

    const int sr = tid >> 3, sc8 = tid & 7;
    const unsigned short* kbase  = kb + kvoff + (size_t)sr * 1024 + sc8 * 8;
    const unsigned short* vtbase = vbT + ((size_t)bh * 64 + sr) * 2048 + sc8 * 8;

    uint4 kx0, kx1, vx0, vx1;
#define LOADW(KW) do { \
        const unsigned short* kp = kbase + (size_t)(KW) * 1024; \
        const unsigned short* vp = vtbase + (KW); \
        kx0 = *(const uint4*)kp;  kx1 = *(const uint4*)(kp + 32 * 1024); \
        vx0 = *(const uint4*)vp;  vx1 = *(const uint4*)(vp + 32 * 2048); \
    } while (0)
#define WRITEW(BUF) do { \
        *(uint4*)&Ks[BUF][sr][sc8 * 8]      = kx0; \
        *(uint4*)&Ks[BUF][sr + 32][sc8 * 8] = kx1; \
        *(uint4*)&Vt[BUF][sr][sc8 * 8]      = vx0; \
        *(uint4*)&Vt[BUF][sr + 32][sc8 * 8] = vx1; \
    } while (0)

    float lrun0 = 0.f, lrun1 = 0.f;
    f32x4 acc[4][2];
#pragma unroll
    for (int db = 0; db < 4; db++) {
        acc[db][0] = (f32x4){0.f, 0.f, 0.f, 0.f};
        acc[db][1] = (f32x4){0.f, 0.f, 0.f, 0.f};
    }

    const float SE = 0.03125f * LOG2E;

    // QK^T on buffer CURN -> exp2 -> packed bf16 P (2 q-frags, shared K reads)
#define QKSM(CURN, PF) do { \
        _Pragma("unroll") \
        for (int kbi = 0; kbi < 4; kbi++) { \
            const unsigned short* kr = &Ks[CURN][kbi * 16 + lq][0]; \
            F8 kf0, kf1; \
            kf0.q = *(const uint4*)(kr + 8 * g); \
            kf1.q = *(const uint4*)(kr + 32 + 8 * g); \
            f32x4 st0 = (f32x4){0.f, 0.f, 0.f, 0.f}; \
            f32x4 st1 = (f32x4){0.f, 0.f, 0.f, 0.f}; \
            st0 = MFMA16(kf0.v, qf[0][0].v, st0); \
            st0 = MFMA16(kf1.v, qf[0][1].v, st0); \
            st1 = MFMA16(kf0.v, qf[1][0].v, st1); \
            st1 = MFMA16(kf1.v, qf[1][1].v, st1); \
            float a0 = fexp2(st0[0] * SE), a1 = fexp2(st0[1] * SE); \
            float a2 = fexp2(st0[2] * SE), a3 = fexp2(st0[3] * SE); \
            float b0 = fexp2(st1[0] * SE), b1 = fexp2(st1[1] * SE); \
            float b2 = fexp2(st1[2] * SE), b3 = fexp2(st1[3] * SE); \
            lrun0 += (a0 + a1) + (a2 + a3); \
            lrun1 += (b0 + b1) + (b2 + b3); \
            unsigned wa0, wa1, wb0, wb1; \
            asm("v_cvt_pk_bf16_f32 %0, %1, %2" : "=v"(wa0) : "v"(a0), "v"(a1)); \
            asm("v_cvt_pk_bf16_f32 %0, %1, %2" : "=v"(wa1) : "v"(a2), "v"(a3)); \
            asm("v_cvt_pk_bf16_f32 %0, %1, %2" : "=v"(wb0) : "v"(b0), "v"(b1)); \
            asm("v_cvt_pk_bf16_f32 %0, %1, %2" : "=v"(wb1) : "v"(b2), "v"(b3)); \
            PF[0][kbi >> 1].u32[(kbi & 1) * 2 + 0] = wa0; \
            PF[0][kbi >> 1].u32[(kbi & 1) * 2 + 1] = wa1; \
            PF[1][kbi >> 1].u32[(kbi & 1) * 2 + 0] = wb0; \
            PF[1][kbi >> 1].u32[(kbi & 1) * 2 + 1] = wb1; \
        } \
    } while (0)

    // PV on buffer CURN: V-frag reads shared across both q-frags
#define PVSTEP(CURN, PF) do { \
        _Pragma("unroll") \
        for (int kg = 0; kg < 2; kg++) { \
            F8 vf0, vf1, vf2, vf3; \
            vf0.q = *(const uint4*)(&Vt[CURN][ 0 + lq][kg * 32] + 8 * g); \
            vf1.q = *(const uint4*)(&Vt[CURN][16 + lq][kg * 32] + 8 * g); \
            vf2.q = *(const uint4*)(&Vt[CURN][32 + lq][kg * 32] + 8 * g); \
            vf3.q = *(const uint4*)(&Vt[CURN][48 + lq][kg * 32] + 8 * g); \
            __builtin_amdgcn_s_setprio(1); \
            acc[0][0] = MFMA16(vf0.v, PF[0][kg].v, acc[0][0]); \
            acc[1][0] = MFMA16(vf1.v, PF[0][kg].v, acc[1][0]); \
            acc[2][0] = MFMA16(vf2.v, PF[0][kg].v, acc[2][0]); \
            acc[3][0] = MFMA16(vf3.v, PF[0][kg].v, acc[3][0]); \
            acc[0][1] = MFMA16(vf0.v, PF[1][kg].v, acc[0][1]); \
            acc[1][1] = MFMA16(vf1.v, PF[1][kg].v, acc[1][1]); \
            acc[2][1] = MFMA16(vf2.v, PF[1][kg].v, acc[2][1]); \
            acc[3][1] = MFMA16(vf3.v, PF[1][kg].v, acc[3][1]); \
            __builtin_amdgcn_s_setprio(0); \
        } \
    } while (0)

    F8 pfA[2][2], pfB[2][2];

    // prologue: fill buf0 + buf1, compute P(0) into pfA
    LOADW(0);
    WRITEW(0);
    LOADW(64);
    __syncthreads();          // buf0 ready
    QKSM(0, pfA);
    WRITEW(1);
    __syncthreads();          // buf1 ready

    // window T: PV reads buf T%3, QK(T+1) reads (T+1)%3, write (T+2)%3.
#define WBODY(BCUR, BNXT, BWR, T, PF_CUR, PF_NXT) do { \
        if ((T) + 2 < 32) LOADW(((T) + 2) * 64); \
        if ((T) + 1 < 32) QKSM(BNXT, PF_NXT); \
        PVSTEP(BCUR, PF_CUR); \
        if ((T) + 2 < 32) WRITEW(BWR); \
        __syncthreads(); \
    } while (0)

    for (int t = 0; t < 30; t += 6) {
        WBODY(0, 1, 2, t + 0, pfA, pfB);
        WBODY(1, 2, 0, t + 1, pfB, pfA);
        WBODY(2, 0, 1, t + 2, pfA, pfB);
        WBODY(0, 1, 2, t + 3, pfB, pfA);
        WBODY(1, 2, 0, t + 4, pfA, pfB);
        WBODY(2, 0, 1, t + 5, pfB, pfA);
    }
    WBODY(0, 1, 2, 30, pfA, pfB);   // window 30 (computes P(31) into pfB)
    WBODY(1, 2, 0, 31, pfB, pfA);   // window 31 (PV only)

    // final l reduction (4 g-groups per query) + store ctx^T, per q-frag
    lrun0 += __shfl_xor(lrun0, 16);
    lrun0 += __shfl_xor(lrun0, 32);
    lrun1 += __shfl_xor(lrun1, 16);
    lrun1 += __shfl_xor(lrun1, 32);
#pragma unroll
    for (int qi = 0; qi < 2; qi++) {
        const float inv = 1.f / (qi ? lrun1 : lrun0);
        const size_t crow = ((size_t)(b * 2048 + qw + qi * 16 + lq)) * 1024 + h * 64;
#pragma unroll
        for (int db = 0; db < 4; db++)
#pragma unroll
            for (int r = 0; r < 4; r++)
                ctx[crow + db * 16 + g * 4 + r] = f2b(acc[db][qi][r] * inv);
    }
#undef LOADW
#undef WRITEW
#undef QKSM
#undef PVSTEP
#undef WBODY
}

// ---------------------------------------------------------------------------
extern "C" void kernel_launch(void* const* d_in, const int* in_sizes, int n_in,
                              void* d_out, int out_size, void* d_ws, size_t ws_size,
                              hipStream_t stream) {
    const float* V  = (const float*)d_in[0];
    const float* Q  = (const float*)d_in[1];
    const float* K  = (const float*)d_in[2];
    const float* Wq = (const float*)d_in[3];
    const float* bq = (const float*)d_in[4];
    const float* Wk = (const float*)d_in[5];
    const float* bk = (const float*)d_in[6];
    const float* Wv = (const float*)d_in[7];
    const float* bv = (const float*)d_in[8];
    const float* Wo = (const float*)d_in[9];
    const float* bo = (const float*)d_in[10];

    const size_t M4 = (size_t)4096 * 1024;
    const size_t M1 = (size_t)1024 * 1024;
    unsigned short* qc  = (unsigned short*)d_ws;
    unsigned short* kc  = qc + M4;
    unsigned short* vc  = kc + M4;
    unsigned short* wtq = vc + M4;
    unsigned short* wtk = wtq + M1;
    unsigned short* wtv = wtk + M1;
    unsigned short* wto = wtv + M1;
    unsigned short* qb  = wto + M1;
    unsigned short* kb  = qb + M4;
    unsigned short* vb  = kb + M4;   // holds V in vbT layout (written by proj z==2)
    unsigned short* ctx = vb + M4;

    prep_kernel<<<dim3(4096, 1, 4), 256, 0, stream>>>(
        Q, K, V, Wq, Wk, Wv, Wo, qc, kc, vc, wtq, wtk, wtv, wto);
    proj_kernel<<<dim3(32, 8, 3), 256, 0, stream>>>(
        qc, kc, vc, wtq, wtk, wtv, bq, bk, bv, qb, kb, vb);
    attn_kernel<<<dim3(16, 32), 256, 0, stream>>>(qb, kb, vb, ctx);
    out_proj_kernel<<<dim3(32, 8), 256, 0, stream>>>(ctx, wto, bo, (float*)d_out);
}